// Round 3
// baseline (380.772 us; speedup 1.0000x reference)
//
#include <hip/hip_runtime.h>
#include <hip/hip_bf16.h>
#include <math.h>

// ---------------- problem constants ----------------
#define BATCH 65536
#define BITS 64
#define HID 512
#define BM 32            // batch rows per block
#define NTHREADS 512     // 8 waves

using f32x4 = __attribute__((ext_vector_type(4))) float;
using s16x8 = __attribute__((ext_vector_type(8))) short;

#define MFMA16(a, b, c) __builtin_amdgcn_mfma_f32_16x16x32_bf16((a), (b), (c), 0, 0, 0)

__device__ __forceinline__ unsigned short f2bf(float f) {
    unsigned u = __builtin_bit_cast(unsigned, f);
    u = u + 0x7FFFu + ((u >> 16) & 1u);   // RNE
    return (unsigned short)(u >> 16);
}

// ---------------- LDS layout (byte offsets) ----------------
// HBUF : [32][512] bf16, row stride 1024B, 16B-granule XOR swizzle (h1, then h2)
// XBUF : [32][64] bf16 rows of 128B, swizzled                      (shift_bits tile)
// REDB : [8 waves][32 rows] {sum,sumsq} f32                        LN partials
// STATB: [32][2] f32 (mu, rsig)
// LOGB : [32][68] f32 logits/probs  (overlays HBUF after GEMM3)
// ABUF : [32][68] f32 a_bits tile   (overlays HBUF+8704)
#define HBUF 0
#define XBUF 32768
#define REDB 36864
#define STATB 38912
#define SMEM_BYTES 39168
#define LOGB 0
#define ABUF 8704
#define LSTRIDE 272

__device__ __forceinline__ int hswz(int row, int k) {
    // 1024B rows, 16B granules, granule ^= (row&7)
    return HBUF + row * 1024 + ((((k >> 3) ^ (row & 7))) << 4) + ((k & 7) << 1);
}
__device__ __forceinline__ int xa(int row, int k) {
    return XBUF + row * 128 + ((((k >> 3) ^ (row & 7))) << 4) + ((k & 7) << 1);
}

// ---------------- weights: f32 [K][N] -> bf16 [N][K] in ws ----------------
// wt1 @ elem 0      : [512][64]
// wt2 @ elem 32768  : [512][512]
// wt3 @ elem 294912 : [64][512]
__global__ void weights_kernel(const float* __restrict__ W1, const float* __restrict__ W2,
                               const float* __restrict__ W3, unsigned short* __restrict__ wt) {
    __shared__ unsigned short tile[32][33];
    int b = blockIdx.x;
    const float* src; unsigned short* dst; int K, N, kt, nt;
    if (b < 32)       { src = W1; dst = wt;          K = 64;  N = 512; kt = b >> 4;        nt = b & 15; }
    else if (b < 288) { int c = b - 32;  src = W2; dst = wt + 32768;  K = 512; N = 512; kt = c >> 4; nt = c & 15; }
    else              { int c = b - 288; src = W3; dst = wt + 294912; K = 512; N = 64;  kt = c >> 1; nt = c & 1;  }
    int tx = threadIdx.x & 31, ty = threadIdx.x >> 5;
    int k0 = kt * 32, n0 = nt * 32;
#pragma unroll
    for (int i = 0; i < 4; i++) {
        int k = k0 + ty + i * 8;
        tile[tx][ty + i * 8] = f2bf(src[(size_t)k * N + n0 + tx]);
    }
    __syncthreads();
#pragma unroll
    for (int i = 0; i < 4; i++) {
        int n = n0 + ty + i * 8;
        dst[(size_t)n * K + k0 + tx] = tile[ty + i * 8][tx];
    }
}

// ---------------- LN helpers (2 row-tiles per wave) ----------------
__device__ __forceinline__ void ln_reduce_write(f32x4 (&acc)[2][4], const float* __restrict__ bias,
                                                char* smem, int n0w, int ln, int g, int wave) {
    float bb[4];
#pragma unroll
    for (int fn = 0; fn < 4; fn++) bb[fn] = bias[n0w + fn * 16 + ln];
#pragma unroll
    for (int fm = 0; fm < 2; fm++)
#pragma unroll
        for (int fn = 0; fn < 4; fn++)
#pragma unroll
            for (int r = 0; r < 4; r++) acc[fm][fn][r] += bb[fn];
#pragma unroll
    for (int fm = 0; fm < 2; fm++)
#pragma unroll
        for (int r = 0; r < 4; r++) {
            float s = 0.f, q = 0.f;
#pragma unroll
            for (int fn = 0; fn < 4; fn++) { float v = acc[fm][fn][r]; s += v; q += v * v; }
#pragma unroll
            for (int m = 1; m < 16; m <<= 1) { s += __shfl_xor(s, m, 64); q += __shfl_xor(q, m, 64); }
            if (ln == 0) {
                int row = fm * 16 + g * 4 + r;
                float* rp = (float*)(smem + REDB + (wave * 32 + row) * 8);
                rp[0] = s; rp[1] = q;
            }
        }
}

__device__ __forceinline__ void ln_stats_finalize(char* smem, int t) {
    if (t < 32) {
        float s = 0.f, q = 0.f;
#pragma unroll
        for (int w = 0; w < 8; w++) {
            float* rp = (float*)(smem + REDB + (w * 32 + t) * 8);
            s += rp[0]; q += rp[1];
        }
        float mu = s * (1.0f / 512.0f);
        float var = q * (1.0f / 512.0f) - mu * mu;
        float rs = rsqrtf(var + 1e-5f);
        float* sp = (float*)(smem + STATB + t * 8);
        sp[0] = mu; sp[1] = rs;
    }
}

__device__ __forceinline__ void ln_apply_store(f32x4 (&acc)[2][4], const float* __restrict__ gamma,
                                               const float* __restrict__ beta, char* smem,
                                               int n0w, int ln, int g) {
    float gm[4], bt[4];
#pragma unroll
    for (int fn = 0; fn < 4; fn++) { int c = n0w + fn * 16 + ln; gm[fn] = gamma[c]; bt[fn] = beta[c]; }
#pragma unroll
    for (int fm = 0; fm < 2; fm++)
#pragma unroll
        for (int r = 0; r < 4; r++) {
            int row = fm * 16 + g * 4 + r;
            float* sp = (float*)(smem + STATB + row * 8);
            float mu = sp[0], rs = sp[1];
#pragma unroll
            for (int fn = 0; fn < 4; fn++) {
                int col = n0w + fn * 16 + ln;
                float y = (acc[fm][fn][r] - mu) * rs * gm[fn] + bt[fn];
                float ge = 0.5f * y * (1.0f + erff(y * 0.70710678118654752f));
                *(unsigned short*)(smem + hswz(row, col)) = f2bf(ge);
            }
        }
}

// ---------------- fused main kernel ----------------
__global__ __launch_bounds__(NTHREADS, 4) void fused_kernel(
    const float* __restrict__ a_bits, const float* __restrict__ shift_bits,
    const float* __restrict__ b1, const float* __restrict__ g1, const float* __restrict__ be1,
    const float* __restrict__ b2, const float* __restrict__ g2, const float* __restrict__ be2,
    const float* __restrict__ b3,
    const unsigned short* __restrict__ wt,
    float* __restrict__ out) {
    __shared__ char smem[SMEM_BYTES];
    const int t = threadIdx.x;
    const int wave = t >> 6, lane = t & 63, g = lane >> 4, ln = lane & 15;
    const int row0 = blockIdx.x * BM;
    const int n0w = wave * 64;
    const unsigned short* wt1 = wt;
    const unsigned short* wt2 = wt + 32768;
    const unsigned short* wt3 = wt + 294912;

    // ---- stage shift_bits tile (f32 -> bf16), 4 elems/thread ----
    {
        int r = t >> 4, G = t & 15;
        const float* xs = shift_bits + (size_t)(row0 + r) * 64 + G * 4;
        float4 x = *(const float4*)xs;
        unsigned p0 = (unsigned)f2bf(x.x) | ((unsigned)f2bf(x.y) << 16);
        unsigned p1 = (unsigned)f2bf(x.z) | ((unsigned)f2bf(x.w) << 16);
        uint2 v; v.x = p0; v.y = p1;
        *(uint2*)(smem + XBUF + r * 128 + (((G >> 1) ^ (r & 7)) << 4) + (G & 1) * 8) = v;
    }
    __syncthreads();

    // per-lane W2 row bases (output col n -> weight row n of wt2 [N][K])
    const unsigned short* b2base[4];
#pragma unroll
    for (int fn = 0; fn < 4; fn++) b2base[fn] = wt2 + (size_t)(n0w + fn * 16 + ln) * 512;

    // ---- GEMM1: x(32x64) @ W1(64x512), B direct from L2 ----
    f32x4 acc[2][4];
#pragma unroll
    for (int fm = 0; fm < 2; fm++)
#pragma unroll
        for (int fn = 0; fn < 4; fn++) acc[fm][fn] = (f32x4){0.f, 0.f, 0.f, 0.f};
#pragma unroll
    for (int ks = 0; ks < 2; ks++) {
        s16x8 af[2], bf[4];
#pragma unroll
        for (int fn = 0; fn < 4; fn++)
            bf[fn] = *(const s16x8*)(wt1 + (size_t)(n0w + fn * 16 + ln) * 64 + ks * 32 + g * 8);
#pragma unroll
        for (int fm = 0; fm < 2; fm++) af[fm] = *(const s16x8*)(smem + xa(fm * 16 + ln, ks * 32 + g * 8));
#pragma unroll
        for (int fm = 0; fm < 2; fm++)
#pragma unroll
            for (int fn = 0; fn < 4; fn++) acc[fm][fn] = MFMA16(af[fm], bf[fn], acc[fm][fn]);
    }

    // ---- LN1 + GELU -> h1 in HBUF ----
    ln_reduce_write(acc, b1, smem, n0w, ln, g, wave);
    __syncthreads();
    ln_stats_finalize(smem, t);
    __syncthreads();
    ln_apply_store(acc, g1, be1, smem, n0w, ln, g);
    __syncthreads();

    // ---- GEMM2: h1(32x512) @ W2(512x512), B direct from L2, no barriers ----
#pragma unroll
    for (int fm = 0; fm < 2; fm++)
#pragma unroll
        for (int fn = 0; fn < 4; fn++) acc[fm][fn] = (f32x4){0.f, 0.f, 0.f, 0.f};
#pragma unroll
    for (int kk = 0; kk < 8; kk++) {
#pragma unroll
        for (int ks = 0; ks < 2; ks++) {
            s16x8 af[2], bf[4];
#pragma unroll
            for (int fn = 0; fn < 4; fn++)
                bf[fn] = *(const s16x8*)(b2base[fn] + kk * 64 + ks * 32 + g * 8);
#pragma unroll
            for (int fm = 0; fm < 2; fm++)
                af[fm] = *(const s16x8*)(smem + hswz(fm * 16 + ln, kk * 64 + ks * 32 + g * 8));
#pragma unroll
            for (int fm = 0; fm < 2; fm++)
#pragma unroll
                for (int fn = 0; fn < 4; fn++) acc[fm][fn] = MFMA16(af[fm], bf[fn], acc[fm][fn]);
        }
    }

    // ---- LN2 + GELU -> h2 overwrites HBUF (all GEMM2 reads drain at 1st barrier) ----
    ln_reduce_write(acc, b2, smem, n0w, ln, g, wave);
    __syncthreads();
    ln_stats_finalize(smem, t);
    __syncthreads();
    ln_apply_store(acc, g2, be2, smem, n0w, ln, g);
    __syncthreads();

    // ---- GEMM3: h2(32x512) @ W3(512x64) -> logits; one 16x16 tile per wave ----
    const int mh = wave >> 2, q = wave & 3;
    float b3v = b3[q * 16 + ln];
    const unsigned short* b3base = wt3 + (size_t)(q * 16 + ln) * 512;
    f32x4 acc3 = (f32x4){0.f, 0.f, 0.f, 0.f};
#pragma unroll
    for (int ks = 0; ks < 16; ks++) {
        s16x8 bfr = *(const s16x8*)(b3base + ks * 32 + g * 8);
        s16x8 af = *(const s16x8*)(smem + hswz(mh * 16 + ln, ks * 32 + g * 8));
        acc3 = MFMA16(af, bfr, acc3);
    }
    __syncthreads();

    // ---- logits (+b3) into LOGB; a_bits tile into ABUF (HBUF now dead) ----
#pragma unroll
    for (int r = 0; r < 4; r++) {
        int row = mh * 16 + g * 4 + r;
        int col = q * 16 + ln;
        *(float*)(smem + LOGB + row * LSTRIDE + col * 4) = acc3[r] + b3v;
    }
    {
        int r = t >> 4, c0 = (t & 15) * 4;
        float4 av = *(const float4*)(a_bits + (size_t)(row0 + r) * 64 + c0);
        *(float4*)(smem + ABUF + r * LSTRIDE + c0 * 4) = av;
    }
    __syncthreads();

    // ---- softmax over 64 (16 threads per row, 4 cols each) ----
    {
        int r = t >> 4, c0 = (t & 15) * 4;
        float* lp = (float*)(smem + LOGB + r * LSTRIDE + c0 * 4);
        float4 v = *(float4*)lp;
        float mx = fmaxf(fmaxf(v.x, v.y), fmaxf(v.z, v.w));
#pragma unroll
        for (int d = 1; d < 16; d <<= 1) mx = fmaxf(mx, __shfl_xor(mx, d, 64));
        float e0 = __expf(v.x - mx), e1 = __expf(v.y - mx);
        float e2 = __expf(v.z - mx), e3 = __expf(v.w - mx);
        float s = e0 + e1 + e2 + e3;
#pragma unroll
        for (int d = 1; d < 16; d <<= 1) s += __shfl_xor(s, d, 64);
        float inv = 1.0f / s;
        float4 o; o.x = e0 * inv; o.y = e1 * inv; o.z = e2 * inv; o.w = e3 * inv;
        *(float4*)lp = o;
    }
    __syncthreads();

    // ---- causal conv: out[i] = sum_s p[s]*a[i-s], 4-wide sliding register window ----
    {
        int r = t >> 4, i0 = (t & 15) * 4;
        const float* prow = (const float*)(smem + LOGB + r * LSTRIDE);
        const float* arow = (const float*)(smem + ABUF + r * LSTRIDE);
        float4 a0 = *(const float4*)(arow + i0);
        float aw0 = a0.x, aw1 = a0.y, aw2 = a0.z, aw3 = a0.w;
        float o0 = 0.f, o1 = 0.f, o2 = 0.f, o3 = 0.f;
#pragma unroll
        for (int s = 0; s < 64; s++) {
            float ps = prow[s];
            o0 = fmaf(ps, aw0, o0);
            o1 = fmaf(ps, aw1, o1);
            o2 = fmaf(ps, aw2, o2);
            o3 = fmaf(ps, aw3, o3);
            int idx = i0 - s - 1;
            float an = (idx >= 0) ? arow[idx] : 0.0f;
            aw3 = aw2; aw2 = aw1; aw1 = aw0; aw0 = an;
        }
        float4 o; o.x = o0; o.y = o1; o.z = o2; o.w = o3;
        *(float4*)(out + (size_t)(row0 + r) * 64 + i0) = o;
    }
}

extern "C" void kernel_launch(void* const* d_in, const int* in_sizes, int n_in,
                              void* d_out, int out_size, void* d_ws, size_t ws_size,
                              hipStream_t stream) {
    const float* a_bits = (const float*)d_in[0];
    const float* shift  = (const float*)d_in[1];
    const float* W1  = (const float*)d_in[2];
    const float* b1  = (const float*)d_in[3];
    const float* g1  = (const float*)d_in[4];
    const float* be1 = (const float*)d_in[5];
    const float* W2  = (const float*)d_in[6];
    const float* b2  = (const float*)d_in[7];
    const float* g2  = (const float*)d_in[8];
    const float* be2 = (const float*)d_in[9];
    const float* W3  = (const float*)d_in[10];
    const float* b3  = (const float*)d_in[11];
    float* out = (float*)d_out;
    unsigned short* wt = (unsigned short*)d_ws;

    weights_kernel<<<320, 256, 0, stream>>>(W1, W2, W3, wt);
    fused_kernel<<<BATCH / BM, NTHREADS, 0, stream>>>(a_bits, shift, b1, g1, be1,
                                                      b2, g2, be2, b3, wt, out);
}

// Round 4
// 217.788 us; speedup vs baseline: 1.7484x; 1.7484x over previous
//
#include <hip/hip_runtime.h>
#include <hip/hip_bf16.h>
#include <math.h>

// ---------------- problem constants ----------------
#define BATCH 65536
#define BITS 64
#define HID 512
#define BM 64            // batch rows per block
#define NTHREADS 512     // 8 waves

using f32x4 = __attribute__((ext_vector_type(4))) float;
using s16x8 = __attribute__((ext_vector_type(8))) short;

#define MFMA16(a, b, c) __builtin_amdgcn_mfma_f32_16x16x32_bf16((a), (b), (c), 0, 0, 0)

__device__ __forceinline__ unsigned short f2bf(float f) {
    unsigned u = __builtin_bit_cast(unsigned, f);
    u = u + 0x7FFFu + ((u >> 16) & 1u);   // RNE
    return (unsigned short)(u >> 16);
}

// ---------------- LDS layout (byte offsets) ----------------
// HBUF : [64][512] bf16, row stride 1024B, 16B-granule XOR swizzle (h1, then h2)
// XBUF : [64][64] bf16 rows of 128B, swizzled                      (shift_bits tile)
// REDB : [64 rows][8 waves] {sum,sumsq} f32                        LN partials
// STATB: [64][2] f32 (mu, rsig)
// LOGB : [64][68] f32 logits/probs  (overlays HBUF after GEMM3)
// ABUF : [64][68] f32 a_bits tile   (overlays HBUF+17408)
#define HBUF 0
#define XBUF 65536
#define REDB 73728
#define STATB 77824
#define SMEM_BYTES 78336
#define LOGB 0
#define ABUF 17408
#define LSTRIDE 272

__device__ __forceinline__ int hswz(int row, int k) {
    // 1024B rows, 16B granules, granule ^= (row&7)
    return HBUF + row * 1024 + ((((k >> 3) ^ (row & 7))) << 4) + ((k & 7) << 1);
}
__device__ __forceinline__ int xa(int row, int k) {
    return XBUF + row * 128 + ((((k >> 3) ^ (row & 7))) << 4) + ((k & 7) << 1);
}

// ---------------- weights: f32 [K][N] -> bf16 [N][K] in ws ----------------
// wt1 @ elem 0      : [512][64]
// wt2 @ elem 32768  : [512][512]
// wt3 @ elem 294912 : [64][512]
__global__ void weights_kernel(const float* __restrict__ W1, const float* __restrict__ W2,
                               const float* __restrict__ W3, unsigned short* __restrict__ wt) {
    __shared__ unsigned short tile[32][33];
    int b = blockIdx.x;
    const float* src; unsigned short* dst; int K, N, kt, nt;
    if (b < 32)       { src = W1; dst = wt;          K = 64;  N = 512; kt = b >> 4;        nt = b & 15; }
    else if (b < 288) { int c = b - 32;  src = W2; dst = wt + 32768;  K = 512; N = 512; kt = c >> 4; nt = c & 15; }
    else              { int c = b - 288; src = W3; dst = wt + 294912; K = 512; N = 64;  kt = c >> 1; nt = c & 1;  }
    int tx = threadIdx.x & 31, ty = threadIdx.x >> 5;
    int k0 = kt * 32, n0 = nt * 32;
#pragma unroll
    for (int i = 0; i < 4; i++) {
        int k = k0 + ty + i * 8;
        tile[tx][ty + i * 8] = f2bf(src[(size_t)k * N + n0 + tx]);
    }
    __syncthreads();
#pragma unroll
    for (int i = 0; i < 4; i++) {
        int n = n0 + ty + i * 8;
        dst[(size_t)n * K + k0 + tx] = tile[ty + i * 8][tx];
    }
}

// ---------------- LN helpers ----------------
__device__ __forceinline__ void ln_reduce_write(f32x4 (&acc)[4][4], const float* __restrict__ bias,
                                                char* smem, int n0w, int ln, int g, int wave) {
    float bb[4];
#pragma unroll
    for (int fn = 0; fn < 4; fn++) bb[fn] = bias[n0w + fn * 16 + ln];
#pragma unroll
    for (int fm = 0; fm < 4; fm++)
#pragma unroll
        for (int fn = 0; fn < 4; fn++)
#pragma unroll
            for (int r = 0; r < 4; r++) acc[fm][fn][r] += bb[fn];
#pragma unroll
    for (int fm = 0; fm < 4; fm++)
#pragma unroll
        for (int r = 0; r < 4; r++) {
            float s = 0.f, q = 0.f;
#pragma unroll
            for (int fn = 0; fn < 4; fn++) { float v = acc[fm][fn][r]; s += v; q += v * v; }
#pragma unroll
            for (int m = 1; m < 16; m <<= 1) { s += __shfl_xor(s, m, 64); q += __shfl_xor(q, m, 64); }
            if (ln == 0) {
                int row = fm * 16 + g * 4 + r;
                float* rp = (float*)(smem + REDB + (row * 8 + wave) * 8);
                rp[0] = s; rp[1] = q;
            }
        }
}

__device__ __forceinline__ void ln_stats_finalize(char* smem, int t) {
    if (t < 64) {
        float s = 0.f, q = 0.f;
#pragma unroll
        for (int w = 0; w < 8; w++) {
            float* rp = (float*)(smem + REDB + (t * 8 + w) * 8);
            s += rp[0]; q += rp[1];
        }
        float mu = s * (1.0f / 512.0f);
        float var = q * (1.0f / 512.0f) - mu * mu;
        float rs = rsqrtf(var + 1e-5f);
        float* sp = (float*)(smem + STATB + t * 8);
        sp[0] = mu; sp[1] = rs;
    }
}

__device__ __forceinline__ void ln_apply_store(f32x4 (&acc)[4][4], const float* __restrict__ gamma,
                                               const float* __restrict__ beta, char* smem,
                                               int n0w, int ln, int g) {
    float gm[4], bt[4];
#pragma unroll
    for (int fn = 0; fn < 4; fn++) { int c = n0w + fn * 16 + ln; gm[fn] = gamma[c]; bt[fn] = beta[c]; }
#pragma unroll
    for (int fm = 0; fm < 4; fm++)
#pragma unroll
        for (int r = 0; r < 4; r++) {
            int row = fm * 16 + g * 4 + r;
            float* sp = (float*)(smem + STATB + row * 8);
            float mu = sp[0], rs = sp[1];
#pragma unroll
            for (int fn = 0; fn < 4; fn++) {
                int col = n0w + fn * 16 + ln;
                float y = (acc[fm][fn][r] - mu) * rs * gm[fn] + bt[fn];
                float ge = 0.5f * y * (1.0f + erff(y * 0.70710678118654752f));
                *(unsigned short*)(smem + hswz(row, col)) = f2bf(ge);
            }
        }
}

// ---------------- fused main kernel ----------------
// launch_bounds(512,2): 256 unified regs/wave -> guaranteed no-spill budget for
// acc(64 AGPR) + depth-4 B-frag pipeline(64) + staging. 1 block/CU, 2 waves/EU.
__global__ __launch_bounds__(NTHREADS, 2) void fused_kernel(
    const float* __restrict__ a_bits, const float* __restrict__ shift_bits,
    const float* __restrict__ b1, const float* __restrict__ g1, const float* __restrict__ be1,
    const float* __restrict__ b2, const float* __restrict__ g2, const float* __restrict__ be2,
    const float* __restrict__ b3,
    const unsigned short* __restrict__ wt,
    float* __restrict__ out) {
    __shared__ char smem[SMEM_BYTES];
    const int t = threadIdx.x;
    const int wave = t >> 6, lane = t & 63, g = lane >> 4, ln = lane & 15;
    const int row0 = blockIdx.x * BM;
    const int n0w = wave * 64;
    const unsigned short* wt1 = wt;
    const unsigned short* wt2 = wt + 32768;
    const unsigned short* wt3 = wt + 294912;

    // ---- issue GEMM1 B-frag loads FIRST (independent of LDS staging) ----
    s16x8 b1f[2][4];
#pragma unroll
    for (int ks = 0; ks < 2; ks++)
#pragma unroll
        for (int fn = 0; fn < 4; fn++)
            b1f[ks][fn] = *(const s16x8*)(wt1 + (size_t)(n0w + fn * 16 + ln) * 64 + ks * 32 + g * 8);

    // ---- stage shift_bits tile (f32 -> bf16) ----
    {
        int r = t >> 3, G = t & 7;
        const float* xs = shift_bits + (size_t)(row0 + r) * 64 + G * 8;
        float4 x0 = *(const float4*)xs;
        float4 x1 = *(const float4*)(xs + 4);
        unsigned p0 = (unsigned)f2bf(x0.x) | ((unsigned)f2bf(x0.y) << 16);
        unsigned p1 = (unsigned)f2bf(x0.z) | ((unsigned)f2bf(x0.w) << 16);
        unsigned p2 = (unsigned)f2bf(x1.x) | ((unsigned)f2bf(x1.y) << 16);
        unsigned p3 = (unsigned)f2bf(x1.z) | ((unsigned)f2bf(x1.w) << 16);
        uint4 v; v.x = p0; v.y = p1; v.z = p2; v.w = p3;
        *(uint4*)(smem + xa(r, G * 8)) = v;
    }
    __syncthreads();

    // per-lane W2 row bases (output col n -> weight row n of wt2 [N][K])
    const unsigned short* b2base[4];
#pragma unroll
    for (int fn = 0; fn < 4; fn++) b2base[fn] = wt2 + (size_t)(n0w + fn * 16 + ln) * 512;

    // ---- GEMM1: x(64x64) @ W1(64x512), B prefetched ----
    f32x4 acc[4][4];
#pragma unroll
    for (int fm = 0; fm < 4; fm++)
#pragma unroll
        for (int fn = 0; fn < 4; fn++) acc[fm][fn] = (f32x4){0.f, 0.f, 0.f, 0.f};
#pragma unroll
    for (int ks = 0; ks < 2; ks++) {
        s16x8 af[4];
#pragma unroll
        for (int fm = 0; fm < 4; fm++) af[fm] = *(const s16x8*)(smem + xa(fm * 16 + ln, ks * 32 + g * 8));
#pragma unroll
        for (int fm = 0; fm < 4; fm++)
#pragma unroll
            for (int fn = 0; fn < 4; fn++) acc[fm][fn] = MFMA16(af[fm], b1f[ks][fn], acc[fm][fn]);
    }

    // ---- LN1 + GELU -> h1 in HBUF ----
    ln_reduce_write(acc, b1, smem, n0w, ln, g, wave);
    __syncthreads();
    ln_stats_finalize(smem, t);
    __syncthreads();
    ln_apply_store(acc, g1, be1, smem, n0w, ln, g);
    __syncthreads();

    // ---- GEMM2: h1(64x512) @ W2(512x512), depth-4 register pipeline on B ----
#pragma unroll
    for (int fm = 0; fm < 4; fm++)
#pragma unroll
        for (int fn = 0; fn < 4; fn++) acc[fm][fn] = (f32x4){0.f, 0.f, 0.f, 0.f};
    // 16 ks-steps of K=32; step s covers k = s*32..s*32+31
    s16x8 bpipe[4][4];
#pragma unroll
    for (int s = 0; s < 4; s++)
#pragma unroll
        for (int fn = 0; fn < 4; fn++)
            bpipe[s][fn] = *(const s16x8*)(b2base[fn] + s * 32 + g * 8);
#pragma unroll
    for (int step = 0; step < 16; step++) {
        s16x8 bf[4];
#pragma unroll
        for (int fn = 0; fn < 4; fn++) bf[fn] = bpipe[step & 3][fn];
        if (step + 4 < 16) {
#pragma unroll
            for (int fn = 0; fn < 4; fn++)
                bpipe[step & 3][fn] = *(const s16x8*)(b2base[fn] + (step + 4) * 32 + g * 8);
        }
        s16x8 af[4];
#pragma unroll
        for (int fm = 0; fm < 4; fm++)
            af[fm] = *(const s16x8*)(smem + hswz(fm * 16 + ln, step * 32 + g * 8));
#pragma unroll
        for (int fm = 0; fm < 4; fm++)
#pragma unroll
            for (int fn = 0; fn < 4; fn++) acc[fm][fn] = MFMA16(af[fm], bf[fn], acc[fm][fn]);
    }

    // a_bits tile -> regs (held through GEMM3; ABUF overlays HBUF which is still live)
    float4 areg0, areg1;
    {
        int r = t >> 3, c0 = (t & 7) * 8;
        const float* ap = a_bits + (size_t)(row0 + r) * 64 + c0;
        areg0 = *(const float4*)ap;
        areg1 = *(const float4*)(ap + 4);
    }

    // ---- LN2 + GELU -> h2 overwrites HBUF (all GEMM2 reads done before 1st barrier) ----
    ln_reduce_write(acc, b2, smem, n0w, ln, g, wave);
    __syncthreads();
    ln_stats_finalize(smem, t);
    __syncthreads();
    ln_apply_store(acc, g2, be2, smem, n0w, ln, g);
    __syncthreads();

    // ---- GEMM3: h2(64x512) @ W3(512x64), depth-8 pipeline on B ----
    const int mh = wave >> 2, q = wave & 3;
    float b3v = b3[q * 16 + ln];
    const unsigned short* b3base = wt3 + (size_t)(q * 16 + ln) * 512;
    f32x4 acc3[2];
    acc3[0] = (f32x4){0.f, 0.f, 0.f, 0.f};
    acc3[1] = (f32x4){0.f, 0.f, 0.f, 0.f};
    s16x8 b3pipe[8];
#pragma unroll
    for (int s = 0; s < 8; s++) b3pipe[s] = *(const s16x8*)(b3base + s * 32 + g * 8);
#pragma unroll
    for (int ks = 0; ks < 16; ks++) {
        s16x8 bfr = b3pipe[ks & 7];
        if (ks + 8 < 16) b3pipe[ks & 7] = *(const s16x8*)(b3base + (ks + 8) * 32 + g * 8);
#pragma unroll
        for (int fm = 0; fm < 2; fm++) {
            s16x8 af = *(const s16x8*)(smem + hswz(mh * 32 + fm * 16 + ln, ks * 32 + g * 8));
            acc3[fm] = MFMA16(af, bfr, acc3[fm]);
        }
    }
    __syncthreads();

    // ---- logits (+b3) and a-tile into LDS (overlay HBUF, now dead) ----
#pragma unroll
    for (int fm = 0; fm < 2; fm++)
#pragma unroll
        for (int r = 0; r < 4; r++) {
            int row = mh * 32 + fm * 16 + g * 4 + r;
            int col = q * 16 + ln;
            *(float*)(smem + LOGB + row * LSTRIDE + col * 4) = acc3[fm][r] + b3v;
        }
    {
        int r = t >> 3, c0 = (t & 7) * 8;
        *(float4*)(smem + ABUF + r * LSTRIDE + c0 * 4) = areg0;
        *(float4*)(smem + ABUF + r * LSTRIDE + c0 * 4 + 16) = areg1;
    }
    __syncthreads();

    // ---- softmax over 64 (8 threads per row) ----
    {
        int r = t >> 3, c0 = (t & 7) * 8;
        float* lp = (float*)(smem + LOGB + r * LSTRIDE + c0 * 4);
        float v[8];
        float4 v0 = *(float4*)lp;
        float4 v1 = *(float4*)(lp + 4);
        v[0] = v0.x; v[1] = v0.y; v[2] = v0.z; v[3] = v0.w;
        v[4] = v1.x; v[5] = v1.y; v[6] = v1.z; v[7] = v1.w;
        float mx = v[0];
#pragma unroll
        for (int j = 1; j < 8; j++) mx = fmaxf(mx, v[j]);
#pragma unroll
        for (int d = 1; d < 8; d <<= 1) mx = fmaxf(mx, __shfl_xor(mx, d, 64));
        float s = 0.f;
#pragma unroll
        for (int j = 0; j < 8; j++) { v[j] = __expf(v[j] - mx); s += v[j]; }
#pragma unroll
        for (int d = 1; d < 8; d <<= 1) s += __shfl_xor(s, d, 64);
        float inv = 1.0f / s;
        float4 o0, o1;
        o0.x = v[0] * inv; o0.y = v[1] * inv; o0.z = v[2] * inv; o0.w = v[3] * inv;
        o1.x = v[4] * inv; o1.y = v[5] * inv; o1.z = v[6] * inv; o1.w = v[7] * inv;
        *(float4*)lp = o0;
        *(float4*)(lp + 4) = o1;
    }
    __syncthreads();

    // ---- causal conv: out[i] = sum_s p[s]*a[i-s], sliding register window ----
    {
        int r = t >> 3, i0 = (t & 7) * 8;
        const float* prow = (const float*)(smem + LOGB + r * LSTRIDE);
        const float* arow = (const float*)(smem + ABUF + r * LSTRIDE);
        float aw[8];
        {
            float4 a0 = *(const float4*)(arow + i0);
            float4 a1 = *(const float4*)(arow + i0 + 4);
            aw[0] = a0.x; aw[1] = a0.y; aw[2] = a0.z; aw[3] = a0.w;
            aw[4] = a1.x; aw[5] = a1.y; aw[6] = a1.z; aw[7] = a1.w;
        }
        float a8[8] = {0.f, 0.f, 0.f, 0.f, 0.f, 0.f, 0.f, 0.f};
#pragma unroll
        for (int s = 0; s < 64; s++) {
            float ps = prow[s];
#pragma unroll
            for (int j = 0; j < 8; j++) a8[j] = fmaf(ps, aw[j], a8[j]);
            int idx = i0 - s - 1;
            float an = (idx >= 0) ? arow[idx] : 0.0f;
            aw[7] = aw[6]; aw[6] = aw[5]; aw[5] = aw[4]; aw[4] = aw[3];
            aw[3] = aw[2]; aw[2] = aw[1]; aw[1] = aw[0]; aw[0] = an;
        }
        float4 o0, o1;
        o0.x = a8[0]; o0.y = a8[1]; o0.z = a8[2]; o0.w = a8[3];
        o1.x = a8[4]; o1.y = a8[5]; o1.z = a8[6]; o1.w = a8[7];
        float* op = out + (size_t)(row0 + r) * 64 + i0;
        *(float4*)op = o0;
        *(float4*)(op + 4) = o1;
    }
}

extern "C" void kernel_launch(void* const* d_in, const int* in_sizes, int n_in,
                              void* d_out, int out_size, void* d_ws, size_t ws_size,
                              hipStream_t stream) {
    const float* a_bits = (const float*)d_in[0];
    const float* shift  = (const float*)d_in[1];
    const float* W1  = (const float*)d_in[2];
    const float* b1  = (const float*)d_in[3];
    const float* g1  = (const float*)d_in[4];
    const float* be1 = (const float*)d_in[5];
    const float* W2  = (const float*)d_in[6];
    const float* b2  = (const float*)d_in[7];
    const float* g2  = (const float*)d_in[8];
    const float* be2 = (const float*)d_in[9];
    const float* W3  = (const float*)d_in[10];
    const float* b3  = (const float*)d_in[11];
    float* out = (float*)d_out;
    unsigned short* wt = (unsigned short*)d_ws;

    weights_kernel<<<320, 256, 0, stream>>>(W1, W2, W3, wt);
    fused_kernel<<<BATCH / BM, NTHREADS, 0, stream>>>(a_bits, shift, b1, g1, be1,
                                                      b2, g2, be2, b3, wt, out);
}